// Round 7
// baseline (191.780 us; speedup 1.0000x reference)
//
#include <hip/hip_runtime.h>
#include <hip/hip_bf16.h>
#include <hip/hip_fp16.h>
#include <cstdint>
#include <cstddef>
#include <type_traits>

#define INTER 2816

typedef __bf16 bf16x8 __attribute__((ext_vector_type(8)));
typedef _Float16 f16x8 __attribute__((ext_vector_type(8)));
typedef float f32x4 __attribute__((ext_vector_type(4)));
typedef unsigned short u16x8 __attribute__((ext_vector_type(8)));
using bf16 = __hip_bfloat16;
using u16 = unsigned short;

__device__ __forceinline__ u16 f2bu(float f) {
  bf16 h = __float2bfloat16(f);
  return *reinterpret_cast<u16*>(&h);
}
__device__ __forceinline__ u16 f2hu(float f) {
  __half h = __float2half(f);
  return *reinterpret_cast<u16*>(&h);
}

// Async global->LDS DMA, 16 B per lane (wave-uniform base + lane*16).
__device__ __forceinline__ void async16(const u16* g, u16* l) {
  __builtin_amdgcn_global_load_lds(
      (const __attribute__((address_space(1))) unsigned int*)g,
      (__attribute__((address_space(3))) unsigned int*)l, 16, 0, 0);
}

// Stage 8 contiguous f32 as bf16 (H=false) or f16 (H=true), 16B out.
template <bool H>
__device__ __forceinline__ void stage8(u16* dst, const float* src) {
  const float4 a = *(const float4*)(src);
  const float4 b = *(const float4*)(src + 4);
  u16 tmp[8];
  if constexpr (H) {
    tmp[0] = f2hu(a.x); tmp[1] = f2hu(a.y); tmp[2] = f2hu(a.z); tmp[3] = f2hu(a.w);
    tmp[4] = f2hu(b.x); tmp[5] = f2hu(b.y); tmp[6] = f2hu(b.z); tmp[7] = f2hu(b.w);
  } else {
    tmp[0] = f2bu(a.x); tmp[1] = f2bu(a.y); tmp[2] = f2bu(a.z); tmp[3] = f2bu(a.w);
    tmp[4] = f2bu(b.x); tmp[5] = f2bu(b.y); tmp[6] = f2bu(b.z); tmp[7] = f2bu(b.w);
  }
  *(uint4*)dst = *(uint4*)tmp;
}

// ---------------------------------------------------------------------------
// Fused one-shot prep. x/wgu stay bf16 (feed the bf16 gateup MFMA); wd, wm2,
// cwb become f16 (feed the f16 pipeline: conv GEMM, deform, gemm2).
// wm2: 64 x INTER f16 (63 metric rows + 1 zero pad). cwb: 9 x INTER f16.
// ---------------------------------------------------------------------------
__global__ __launch_bounds__(256)
void prep_all(const float* __restrict__ x, const float* __restrict__ wgu,
              const float* __restrict__ wd, const float* __restrict__ w_metric,
              const float* __restrict__ conv_w, u16* __restrict__ xbf,
              u16* __restrict__ wgubf, u16* __restrict__ wdbf,
              u16* __restrict__ wm2, u16* __restrict__ cwb) {
  constexpr size_t S0 = (size_t)2048 * 1024;
  constexpr size_t S1 = (size_t)5632 * 1024;
  constexpr size_t S2 = (size_t)1024 * 2816;
  constexpr size_t NCONV_THREADS = (S0 + S1 + S2) / 8;  // 1343488 = 5248 blks
  const size_t t = (size_t)blockIdx.x * 256 + threadIdx.x;
  if (t < NCONV_THREADS) {
    const size_t e0 = t * 8;
    if (e0 < S0) {
      stage8<false>(xbf + e0, x + e0);
    } else if (e0 < S0 + S1) {
      stage8<false>(wgubf + (e0 - S0), wgu + (e0 - S0));
    } else {
      stage8<true>(wdbf + (e0 - S0 - S1), wd + (e0 - S0 - S1));
    }
  } else {
    const unsigned p = (unsigned)(t - NCONV_THREADS);  // 0..205567 (73 rows)
    const unsigned y = p / 2816u;                      // 0..72
    const unsigned c = p - y * 2816u;
    if (y < 64) {
      float v = 0.f;
      if (y < 63) {
        const unsigned o = y / 9, tap = y - o * 9;
        v = w_metric[((size_t)o * INTER + c) * 9 + tap];
      }
      wm2[(size_t)y * INTER + c] = f2hu(v);
    } else {
      const unsigned k = y - 64;
      cwb[(size_t)k * INTER + c] = f2hu(conv_w[(size_t)c * 9 + k]);
    }
  }
}

// ---------------------------------------------------------------------------
// NT GEMM (f16), 128xBN tile. T3/T4 schedule: BK=32 half-tiles ping-pong with
// RAW s_barrier + COUNTED vmcnt (prefetch of next half stays in flight across
// the barrier; __syncthreads would drain it — the documented ~20% stall).
// Per half: {issue next-half loads; vmcnt(NLD) [vmcnt(0) on last]; s_barrier;
// sched_barrier(0); ds_read+MFMA; s_barrier}. Same 32 KB LDS, 3 blocks/CU.
// Exit barrier is safe: each wave's ds_reads complete before its barrier
// (lgkmcnt inserted before MFMA uses), so next prefetch can't clobber.
// NSWAP: n-tile on blockIdx.x for XCD pinning of B. Split-K via grid.z.
// ---------------------------------------------------------------------------
template <int BN, bool NSWAP, typename OT>
__global__ __launch_bounds__(256, 3)
void gemm_nt(const u16* __restrict__ A, int lda, const u16* __restrict__ Bt,
             int ldb, OT* __restrict__ C, int M, int ldc, int K) {
  constexpr int NJ = BN / 32;      // j-tiles per wave
  constexpr int BHALF = BN * 32;   // u16 per B half-tile
  __shared__ u16 As[2 * 128 * 32];
  __shared__ u16 Bs[2 * BHALF];
  const size_t koff = (size_t)blockIdx.z * K;
  A += koff;
  Bt += koff;
  C += (size_t)blockIdx.z * M * ldc;
  const int m0 = (NSWAP ? blockIdx.y : blockIdx.x) * 128;
  const int n0 = (NSWAP ? blockIdx.x : blockIdx.y) * BN;
  const int tid = threadIdx.x;
  const int lane = tid & 63;
  const int wv = tid >> 6;
  const int wm = wv & 1, wn = wv >> 1;
  const int lr = lane & 15;
  const int lq = lane >> 4;

  f32x4 acc[4][NJ];
#pragma unroll
  for (int i = 0; i < 4; ++i)
#pragma unroll
    for (int j = 0; j < NJ; ++j) acc[i][j] = (f32x4){0.f, 0.f, 0.f, 0.f};

  const int srow = tid >> 2;
  const int scol = (tid & 3) * 8;
  const u16* gA0 = A + (size_t)(m0 + srow) * lda + scol;
  const u16* gA1 = A + (size_t)(m0 + 64 + srow) * lda + scol;
  const u16* gB0 = Bt + (size_t)(n0 + srow) * ldb + scol;
  const u16* gB1 = Bt + (size_t)(n0 + 64 + srow) * ldb + scol;  // BN==128 only

  // stage half at K-offset kh into buffer bi (NLD loads per wave)
  auto stage = [&](int kh, int bi) {
    async16(gA0 + kh, As + bi * 4096 + tid * 8);
    async16(gA1 + kh, As + bi * 4096 + 2048 + tid * 8);
    async16(gB0 + kh, Bs + bi * BHALF + tid * 8);
    if constexpr (BN == 128) async16(gB1 + kh, Bs + bi * BHALF + 2048 + tid * 8);
  };

  const int nh = K >> 5;           // number of BK=32 halves
  stage(0, 0);                     // prologue

  for (int hh = 0; hh < nh; ++hh) {
    const int p = hh & 1;
    if (hh + 1 < nh) {
      stage((hh + 1) * 32, p ^ 1);           // prefetch stays in flight
      if constexpr (BN == 128)
        asm volatile("s_waitcnt vmcnt(4)" ::: "memory");
      else
        asm volatile("s_waitcnt vmcnt(3)" ::: "memory");
    } else {
      asm volatile("s_waitcnt vmcnt(0)" ::: "memory");
    }
    __builtin_amdgcn_s_barrier();            // all waves' current half landed
    __builtin_amdgcn_sched_barrier(0);       // pin ds_reads below barrier

    f16x8 af[4], bfr[NJ];
#pragma unroll
    for (int i = 0; i < 4; ++i)
      af[i] = *(const f16x8*)(&As[p * 4096 + (wm * 64 + i * 16 + lr) * 32 + lq * 8]);
#pragma unroll
    for (int j = 0; j < NJ; ++j)
      bfr[j] = *(const f16x8*)(&Bs[p * BHALF + (wn * (BN / 2) + j * 16 + lr) * 32 + lq * 8]);
#pragma unroll
    for (int i = 0; i < 4; ++i)
#pragma unroll
      for (int j = 0; j < NJ; ++j)
        acc[i][j] = __builtin_amdgcn_mfma_f32_16x16x32_f16(af[i], bfr[j],
                                                           acc[i][j], 0, 0, 0);
    __builtin_amdgcn_sched_barrier(0);       // pin next prefetch above nothing
    __builtin_amdgcn_s_barrier();            // all waves done reading buf p
  }

#pragma unroll
  for (int i = 0; i < 4; ++i)
#pragma unroll
    for (int j = 0; j < NJ; ++j) {
      const int col = n0 + wn * (BN / 2) + j * 16 + lr;
#pragma unroll
      for (int r = 0; r < 4; ++r) {
        const int row = m0 + wm * 64 + i * 16 + lq * 4 + r;
        const float v = acc[i][j][r];
        if constexpr (std::is_same_v<OT, float>) {
          C[(size_t)row * ldc + col] = v;
        } else {
          C[(size_t)row * ldc + col] = f2hu(v);
        }
      }
    }
}

// ---------------------------------------------------------------------------
// out[i] = sum of 4 split-K partials (f32), float4-vectorized.
// ---------------------------------------------------------------------------
__global__ void reduce4(const float* __restrict__ q2, float* __restrict__ out) {
  const size_t i = ((size_t)blockIdx.x * 256 + threadIdx.x) * 4;
  const size_t S = (size_t)2048 * 1024;
  float4 a = *(const float4*)(q2 + i);
  const float4 b = *(const float4*)(q2 + S + i);
  const float4 c = *(const float4*)(q2 + 2 * S + i);
  const float4 d = *(const float4*)(q2 + 3 * S + i);
  a.x += b.x + c.x + d.x;
  a.y += b.y + c.y + d.y;
  a.z += b.z + c.z + d.z;
  a.w += b.w + c.w + d.w;
  *(float4*)(out + i) = a;
}

// ---------------------------------------------------------------------------
// qsum = sum of 11 split-K partials of the metric-conv GEMM output.
// ---------------------------------------------------------------------------
__global__ __launch_bounds__(256)
void presum11(const float* __restrict__ q, float* __restrict__ qsum) {
  const size_t i = ((size_t)blockIdx.x * 256 + threadIdx.x) * 4;
  float4 s = *(const float4*)(q + i);
#pragma unroll
  for (int ks = 1; ks < 11; ++ks) {
    const float4 v = *(const float4*)(q + (size_t)ks * 131072 + i);
    s.x += v.x; s.y += v.y; s.z += v.z; s.w += v.w;
  }
  *(float4*)(qsum + i) = s;
}

// ---------------------------------------------------------------------------
// Fused gate/up GEMM + SiLU (bf16 MFMA, f16 out), 128x64 tile, T3/T4
// half-tile ping-pong schedule (see gemm_nt). 32 KB LDS, 3 blocks/CU.
// Grid (44, 16): B-tiles XCD-pinned.
// ---------------------------------------------------------------------------
__global__ __launch_bounds__(256, 3)
void gateup_gemm(const u16* __restrict__ x, const u16* __restrict__ wgu,
                 u16* __restrict__ xffn) {
  constexpr int K = 1024;
  __shared__ u16 As[2 * 128 * 32];
  __shared__ u16 Bgs[2 * 64 * 32];
  __shared__ u16 Bus[2 * 64 * 32];
  const int n0 = blockIdx.x * 64;   // 44 n-tiles (fast dim -> XCD pinning)
  const int m0 = blockIdx.y * 128;  // 16 m-tiles
  const int tid = threadIdx.x;
  const int lane = tid & 63;
  const int wv = tid >> 6;
  const int wm = wv & 1, wn = wv >> 1;
  const int lr = lane & 15;
  const int lq = lane >> 4;

  f32x4 accg[4][2], accu[4][2];
#pragma unroll
  for (int i = 0; i < 4; ++i)
#pragma unroll
    for (int j = 0; j < 2; ++j) {
      accg[i][j] = (f32x4){0.f, 0.f, 0.f, 0.f};
      accu[i][j] = (f32x4){0.f, 0.f, 0.f, 0.f};
    }

  const int srow = tid >> 2;
  const int scol = (tid & 3) * 8;
  const u16* gA0 = x + (size_t)(m0 + srow) * K + scol;
  const u16* gA1 = x + (size_t)(m0 + 64 + srow) * K + scol;
  const u16* gBg = wgu + (size_t)(n0 + srow) * K + scol;
  const u16* gBu = wgu + (size_t)(INTER + n0 + srow) * K + scol;

  auto stage = [&](int kh, int bi) {     // 4 loads per wave
    async16(gA0 + kh, As + bi * 4096 + tid * 8);
    async16(gA1 + kh, As + bi * 4096 + 2048 + tid * 8);
    async16(gBg + kh, Bgs + bi * 2048 + tid * 8);
    async16(gBu + kh, Bus + bi * 2048 + tid * 8);
  };

  constexpr int NH = K >> 5;       // 32 halves
  stage(0, 0);

  for (int hh = 0; hh < NH; ++hh) {
    const int p = hh & 1;
    if (hh + 1 < NH) {
      stage((hh + 1) * 32, p ^ 1);
      asm volatile("s_waitcnt vmcnt(4)" ::: "memory");
    } else {
      asm volatile("s_waitcnt vmcnt(0)" ::: "memory");
    }
    __builtin_amdgcn_s_barrier();
    __builtin_amdgcn_sched_barrier(0);

    bf16x8 af[4], bg[2], bu[2];
#pragma unroll
    for (int i = 0; i < 4; ++i)
      af[i] = *(const bf16x8*)(&As[p * 4096 + (wm * 64 + i * 16 + lr) * 32 + lq * 8]);
#pragma unroll
    for (int j = 0; j < 2; ++j) {
      bg[j] = *(const bf16x8*)(&Bgs[p * 2048 + (wn * 32 + j * 16 + lr) * 32 + lq * 8]);
      bu[j] = *(const bf16x8*)(&Bus[p * 2048 + (wn * 32 + j * 16 + lr) * 32 + lq * 8]);
    }
#pragma unroll
    for (int i = 0; i < 4; ++i)
#pragma unroll
      for (int j = 0; j < 2; ++j) {
        accg[i][j] = __builtin_amdgcn_mfma_f32_16x16x32_bf16(af[i], bg[j],
                                                             accg[i][j], 0, 0, 0);
        accu[i][j] = __builtin_amdgcn_mfma_f32_16x16x32_bf16(af[i], bu[j],
                                                             accu[i][j], 0, 0, 0);
      }
    __builtin_amdgcn_sched_barrier(0);
    __builtin_amdgcn_s_barrier();
  }

#pragma unroll
  for (int i = 0; i < 4; ++i)
#pragma unroll
    for (int j = 0; j < 2; ++j) {
      const int col = n0 + wn * 32 + j * 16 + lr;
#pragma unroll
      for (int r = 0; r < 4; ++r) {
        const int row = m0 + wm * 64 + i * 16 + lq * 4 + r;
        const float g = accg[i][j][r];
        const float u = accu[i][j][r];
        const float s = g / (1.f + __expf(-g));
        xffn[(size_t)row * INTER + col] = f2hu(s * u);  // f16 out
      }
    }
}

// ---------------------------------------------------------------------------
// Fused: 9-tap shifted sum + offsets -> tap records, reading the presummed
// q plane. 256 threads cooperate on the window load; wave 0 computes the
// 64 pixels after the barrier. (f32 path, unchanged.)
// ---------------------------------------------------------------------------
__global__ __launch_bounds__(256)
void offsets_fused(const float* __restrict__ qsum,  // [2048][64]
                   const float* __restrict__ b_metric,
                   float4* __restrict__ wrec, int4* __restrict__ orec) {
  __shared__ float lds[130 * 65];
  const int chunk = blockIdx.x;      // 0..31
  const int b = chunk >> 4;
  const int c0 = (chunk & 15) * 64;
  const int t = threadIdx.x;         // 0..255

  for (int v = t; v < 130 * 16; v += 256) {
    const int row = v >> 4;
    const int c4 = (v & 15) * 4;
    int pg = c0 - 33 + row;
    pg = min(max(pg, 0), 1023);
    const float4 s = *(const float4*)(qsum + ((size_t)b * 1024 + pg) * 64 + c4);
    float* d = &lds[row * 65 + c4];
    d[0] = s.x; d[1] = s.y; d[2] = s.z; d[3] = s.w;
  }
  __syncthreads();
  if (t >= 64) return;

  const int pix = c0 + t;
  const int i = pix >> 5, j = pix & 31;
  float p[7];
#pragma unroll
  for (int o = 0; o < 7; ++o) p[o] = b_metric[o];
#pragma unroll
  for (int tap = 0; tap < 9; ++tap) {
    const int dy = tap / 3 - 1, dx = tap % 3 - 1;
    const int ii = i + dy, jj = j + dx;
    if ((unsigned)ii < 32u && (unsigned)jj < 32u) {
      const float* r = &lds[(t + 33 + dy * 32 + dx) * 65 + tap];
#pragma unroll
      for (int o = 0; o < 7; ++o) p[o] += r[o * 9];
    }
  }
  const float m00 = p[0], m01 = p[1], m10 = p[2], m11 = p[3];
  const float dry = p[4], drx = p[5];
  const float sc = tanhf(p[6]);
#pragma unroll
  for (int k = 0; k < 9; ++k) {
    const float pyk = (float)(k / 3 - 1), pxk = (float)(k % 3 - 1);
    const float offy = sc * (m00 * pyk + m01 * pxk) + dry;
    const float offx = sc * (m10 * pyk + m11 * pxk) + drx;
    const float posy = (float)i + pyk + offy;
    const float posx = (float)j + pxk + offx;
    const float y0f = floorf(posy), x0f = floorf(posx);
    const int y0 = (int)y0f, x0 = (int)x0f;
    const float ty = posy - y0f, tx = posx - x0f;
    const int y1 = y0 + 1, x1 = x0 + 1;
    const float vy0 = ((unsigned)y0 < 32u) ? 1.f : 0.f;
    const float vy1 = ((unsigned)y1 < 32u) ? 1.f : 0.f;
    const float vx0 = ((unsigned)x0 < 32u) ? 1.f : 0.f;
    const float vx1 = ((unsigned)x1 < 32u) ? 1.f : 0.f;
    float4 w;
    w.x = (1.f - ty) * (1.f - tx) * vy0 * vx0;
    w.y = (1.f - ty) * tx * vy0 * vx1;
    w.z = ty * (1.f - tx) * vy1 * vx0;
    w.w = ty * tx * vy1 * vx1;
    const int cy0 = min(max(y0, 0), 31), cy1 = min(max(y1, 0), 31);
    const int cx0 = min(max(x0, 0), 31), cx1 = min(max(x1, 0), 31);
    int4 o;
    o.x = (cy0 * 32 + cx0) * (INTER * 2);  // byte offsets within batch image
    o.y = (cy0 * 32 + cx1) * (INTER * 2);
    o.z = (cy1 * 32 + cx0) * (INTER * 2);
    o.w = (cy1 * 32 + cx1) * (INTER * 2);
    const size_t r = (((size_t)b * 9 + k) << 10) + pix;
    wrec[r] = w;
    orec[r] = o;
  }
}

// ---------------------------------------------------------------------------
// Deformable depthwise conv, 8 channels/thread, PACKED f16 math
// (v_pk_fma_f16 via __hfma2). Records LDS-staged; XCD-local swizzle.
// ---------------------------------------------------------------------------
__global__ __launch_bounds__(256)
void deform_kernel(const u16* __restrict__ xffn,      // f16
                   const float4* __restrict__ wrec,
                   const int4* __restrict__ orec,
                   const u16* __restrict__ cwb,       // f16
                   const float* __restrict__ conv_b,
                   u16* __restrict__ gridout) {       // f16
  __shared__ float4 sw[2][9];
  __shared__ int4 so[2][9];
  const unsigned bid = (blockIdx.x & 7u) * 352u + (blockIdx.x >> 3);
  const unsigned t0 = bid * 256;
  const unsigned p0 = t0 / 352u;          // first pixel touched by block
  const unsigned t = t0 + threadIdx.x;
  const unsigned pix = t / 352u;
  const unsigned cv = t - pix * 352u;
  const int c0 = cv * 8;
  const int b = pix >> 10, l = pix & 1023;

  if (threadIdx.x < 36) {                 // 2 pixels x 9 taps x {wrec,orec}
    const int pp = threadIdx.x / 18;
    const int rr = threadIdx.x - pp * 18;
    const int k = (rr < 9) ? rr : rr - 9;
    const unsigned pixel = p0 + pp;
    if (pixel < 2048) {
      const int bb = pixel >> 10, ll = pixel & 1023;
      const size_t r = (((size_t)bb * 9 + k) << 10) + ll;
      if (rr < 9) sw[pp][k] = wrec[r];
      else        so[pp][k] = orec[r];
    }
  }
  __syncthreads();

  const int pp = (int)(pix - p0);         // 0 or 1

  union U8 { u16x8 u; __half2 h[4]; uint4 q; };

  __half2 acc2[4];
  {
    const float4 b0 = *(const float4*)(&conv_b[c0]);
    const float4 b1 = *(const float4*)(&conv_b[c0 + 4]);
    acc2[0] = __floats2half2_rn(b0.x, b0.y);
    acc2[1] = __floats2half2_rn(b0.z, b0.w);
    acc2[2] = __floats2half2_rn(b1.x, b1.y);
    acc2[3] = __floats2half2_rn(b1.z, b1.w);
  }
  const char* xb = (const char*)xffn +
                   ((size_t)b * 1024 * INTER + c0) * sizeof(u16);
#pragma unroll
  for (int k = 0; k < 9; ++k) {
    const float4 w = sw[pp][k];
    const int4 o = so[pp][k];
    const __half2 wx = __float2half2_rn(w.x);
    const __half2 wy = __float2half2_rn(w.y);
    const __half2 wz = __float2half2_rn(w.z);
    const __half2 ww = __float2half2_rn(w.w);
    U8 v00, v01, v10, v11, cw;
    v00.u = *(const u16x8*)(xb + o.x);
    v01.u = *(const u16x8*)(xb + o.y);
    v10.u = *(const u16x8*)(xb + o.z);
    v11.u = *(const u16x8*)(xb + o.w);
    cw.u = *(const u16x8*)(&cwb[(size_t)k * INTER + c0]);
#pragma unroll
    for (int p = 0; p < 4; ++p) {
      __half2 bl = __hmul2(wx, v00.h[p]);
      bl = __hfma2(wy, v01.h[p], bl);
      bl = __hfma2(wz, v10.h[p], bl);
      bl = __hfma2(ww, v11.h[p], bl);
      acc2[p] = __hfma2(bl, cw.h[p], acc2[p]);
    }
  }
  U8 outv;
#pragma unroll
  for (int p = 0; p < 4; ++p) outv.h[p] = acc2[p];
  *(uint4*)(gridout + ((size_t)b * 1024 + l) * INTER + c0) = outv.q;
}

// ---------------------------------------------------------------------------
extern "C" void kernel_launch(void* const* d_in, const int* in_sizes, int n_in,
                              void* d_out, int out_size, void* d_ws,
                              size_t ws_size, hipStream_t stream) {
  const float* x         = (const float*)d_in[0];
  const float* w_gate_up = (const float*)d_in[1];
  const float* w_metric  = (const float*)d_in[2];
  const float* b_metric  = (const float*)d_in[3];
  const float* conv_w    = (const float*)d_in[4];
  const float* conv_b    = (const float*)d_in[5];
  const float* w_down    = (const float*)d_in[6];
  float* out = (float*)d_out;

  // Workspace (~50 MB peak). Lifetimes:
  //   gridout [0, 11.53)  f16    step 5 -> 6
  //   q2      [12, 44)    f32    step 6 -> 7; region shared (earlier steps):
  //     xffn   [12, 23.6)  f16   step 2 -> 5
  //     xbf    [24, 28.2)  bf16  step 1 -> 2
  //     wgubf  [28.25, 39.8) bf16 step 1 -> 2
  //     q_conv [28.25, 34.1) f32 step 3 -> 4a (11 partials, overlays wgubf)
  //     qsum   [36, 36.5)  f32   step 4a -> 4b
  //     wm2    [40, 40.36) f16   step 1 -> 3 (64 rows)
  //     cwb    [41, 41.05) f16   step 1 -> 5
  //     wrec   [42, 42.3)  f32x4 step 4 -> 5
  //     orec   [43, 43.3)  int4  step 4 -> 5
  //   wdbf    [44, 49.8)  f16    step 1 -> 6
  char* w = (char*)d_ws;
  u16* gridout  = (u16*)(w);
  float* q2     = (float*)(w + (12u << 20));
  u16* xffn     = (u16*)(w + (12u << 20));
  u16* xbf      = (u16*)(w + (24u << 20));
  u16* wgubf    = (u16*)(w + (28u << 20) + (256u << 10));
  float* q_conv = (float*)(w + (28u << 20) + (256u << 10));
  float* qsum   = (float*)(w + (36u << 20));
  u16* wm2      = (u16*)(w + (40u << 20));
  u16* cwb      = (u16*)(w + (41u << 20));
  float4* wrec  = (float4*)(w + (42u << 20));
  int4* orec    = (int4*)(w + (43u << 20));
  u16* wdbf     = (u16*)(w + (44u << 20));

  // 1) fused bf16/f16 conversions + weight repacks
  prep_all<<<6051, 256, 0, stream>>>(x, w_gate_up, w_down, w_metric, conv_w,
                                     xbf, wgubf, wdbf, wm2, cwb);
  // 2) x_ffn = silu(x@Wg^T) * (x@Wu^T)  (T3/T4 schedule; grid (44,16))
  gateup_gemm<<<dim3(44, 16), 256, 0, stream>>>(xbf, wgubf, xffn);
  // 3) metric conv as GEMM (f16), BN=64, split-K x11 (K=256)
  gemm_nt<64, false, float><<<dim3(16, 1, 11), 256, 0, stream>>>(
      xffn, INTER, wm2, INTER, q_conv, 2048, 64, 256);
  // 4a) full-parallelism partial-sum (11 planes -> 1)
  presum11<<<128, 256, 0, stream>>>(q_conv, qsum);
  // 4b) fused tap-sum + offsets -> tap records (256-thread window load)
  offsets_fused<<<32, 256, 0, stream>>>(qsum, b_metric, wrec, orec);
  // 5) deformable depthwise conv (packed f16 math, LDS-staged records)
  deform_kernel<<<2816, 256, 0, stream>>>(xffn, wrec, orec, cwb, conv_b,
                                          gridout);
  // 6) GEMM2 (f16) split-K x4, grid (8,16,4) n-fast: wdbf B-tiles XCD-pinned
  gemm_nt<128, true, float><<<dim3(8, 16, 4), 256, 0, stream>>>(
      gridout, INTER, wdbf, INTER, q2, 2048, 1024, 704);
  // 7) out = sum of 4 partials (deterministic, no cross-XCD atomics)
  reduce4<<<2048, 256, 0, stream>>>(q2, out);
}

// Round 8
// 189.410 us; speedup vs baseline: 1.0125x; 1.0125x over previous
//
#include <hip/hip_runtime.h>
#include <hip/hip_bf16.h>
#include <hip/hip_fp16.h>
#include <cstdint>
#include <cstddef>
#include <type_traits>

#define INTER 2816

typedef __bf16 bf16x8 __attribute__((ext_vector_type(8)));
typedef _Float16 f16x8 __attribute__((ext_vector_type(8)));
typedef float f32x4 __attribute__((ext_vector_type(4)));
typedef unsigned short u16x8 __attribute__((ext_vector_type(8)));
using bf16 = __hip_bfloat16;
using u16 = unsigned short;

__device__ __forceinline__ u16 f2bu(float f) {
  bf16 h = __float2bfloat16(f);
  return *reinterpret_cast<u16*>(&h);
}
__device__ __forceinline__ u16 f2hu(float f) {
  __half h = __float2half(f);
  return *reinterpret_cast<u16*>(&h);
}

// Async global->LDS DMA, 16 B per lane (wave-uniform base + lane*16).
__device__ __forceinline__ void async16(const u16* g, u16* l) {
  __builtin_amdgcn_global_load_lds(
      (const __attribute__((address_space(1))) unsigned int*)g,
      (__attribute__((address_space(3))) unsigned int*)l, 16, 0, 0);
}

// Stage 8 contiguous f32 as bf16 (H=false) or f16 (H=true), 16B out.
template <bool H>
__device__ __forceinline__ void stage8(u16* dst, const float* src) {
  const float4 a = *(const float4*)(src);
  const float4 b = *(const float4*)(src + 4);
  u16 tmp[8];
  if constexpr (H) {
    tmp[0] = f2hu(a.x); tmp[1] = f2hu(a.y); tmp[2] = f2hu(a.z); tmp[3] = f2hu(a.w);
    tmp[4] = f2hu(b.x); tmp[5] = f2hu(b.y); tmp[6] = f2hu(b.z); tmp[7] = f2hu(b.w);
  } else {
    tmp[0] = f2bu(a.x); tmp[1] = f2bu(a.y); tmp[2] = f2bu(a.z); tmp[3] = f2bu(a.w);
    tmp[4] = f2bu(b.x); tmp[5] = f2bu(b.y); tmp[6] = f2bu(b.z); tmp[7] = f2bu(b.w);
  }
  *(uint4*)dst = *(uint4*)tmp;
}

// ---------------------------------------------------------------------------
// Fused one-shot prep. x/wgu stay bf16 (feed the bf16 gateup MFMA); wd, wm2,
// cwb become f16 (feed the f16 pipeline: conv GEMM, deform, gemm2).
// wm2: 64 x INTER f16 (63 metric rows + 1 zero pad). cwb: 9 x INTER f16.
// ---------------------------------------------------------------------------
__global__ __launch_bounds__(256)
void prep_all(const float* __restrict__ x, const float* __restrict__ wgu,
              const float* __restrict__ wd, const float* __restrict__ w_metric,
              const float* __restrict__ conv_w, u16* __restrict__ xbf,
              u16* __restrict__ wgubf, u16* __restrict__ wdbf,
              u16* __restrict__ wm2, u16* __restrict__ cwb) {
  constexpr size_t S0 = (size_t)2048 * 1024;
  constexpr size_t S1 = (size_t)5632 * 1024;
  constexpr size_t S2 = (size_t)1024 * 2816;
  constexpr size_t NCONV_THREADS = (S0 + S1 + S2) / 8;  // 1343488 = 5248 blks
  const size_t t = (size_t)blockIdx.x * 256 + threadIdx.x;
  if (t < NCONV_THREADS) {
    const size_t e0 = t * 8;
    if (e0 < S0) {
      stage8<false>(xbf + e0, x + e0);
    } else if (e0 < S0 + S1) {
      stage8<false>(wgubf + (e0 - S0), wgu + (e0 - S0));
    } else {
      stage8<true>(wdbf + (e0 - S0 - S1), wd + (e0 - S0 - S1));
    }
  } else {
    const unsigned p = (unsigned)(t - NCONV_THREADS);  // 0..205567 (73 rows)
    const unsigned y = p / 2816u;                      // 0..72
    const unsigned c = p - y * 2816u;
    if (y < 64) {
      float v = 0.f;
      if (y < 63) {
        const unsigned o = y / 9, tap = y - o * 9;
        v = w_metric[((size_t)o * INTER + c) * 9 + tap];
      }
      wm2[(size_t)y * INTER + c] = f2hu(v);
    } else {
      const unsigned k = y - 64;
      cwb[(size_t)k * INTER + c] = f2hu(conv_w[(size_t)c * 9 + k]);
    }
  }
}

// ---------------------------------------------------------------------------
// NT GEMM (f16 inputs), 128xBN tile, BK=64 staged as two BK=32 half-tiles
// (single buffer, one barrier-pair per 64 K-elements). 4 waves (2m x 2n),
// 16x16x32 f16 mfma. NSWAP puts the n-tile on blockIdx.x for XCD pinning
// of B. Split-K via grid.z writes partial C at z*M*ldc. K mult of 64.
// (T3/T4 counted-vmcnt variant benched neutral at these occupancies — the
// barrier drain is already hidden by 3-blocks/CU cross-block overlap.)
// ---------------------------------------------------------------------------
template <int BN, bool NSWAP, typename OT>
__global__ __launch_bounds__(256, 3)
void gemm_nt(const u16* __restrict__ A, int lda, const u16* __restrict__ Bt,
             int ldb, OT* __restrict__ C, int M, int ldc, int K) {
  constexpr int NJ = BN / 32;      // j-tiles per wave
  constexpr int BHALF = BN * 32;   // u16 per B half-tile
  __shared__ u16 As[2 * 128 * 32];
  __shared__ u16 Bs[2 * BHALF];
  const size_t koff = (size_t)blockIdx.z * K;
  A += koff;
  Bt += koff;
  C += (size_t)blockIdx.z * M * ldc;
  const int m0 = (NSWAP ? blockIdx.y : blockIdx.x) * 128;
  const int n0 = (NSWAP ? blockIdx.x : blockIdx.y) * BN;
  const int tid = threadIdx.x;
  const int lane = tid & 63;
  const int wv = tid >> 6;
  const int wm = wv & 1, wn = wv >> 1;
  const int lr = lane & 15;
  const int lq = lane >> 4;

  f32x4 acc[4][NJ];
#pragma unroll
  for (int i = 0; i < 4; ++i)
#pragma unroll
    for (int j = 0; j < NJ; ++j) acc[i][j] = (f32x4){0.f, 0.f, 0.f, 0.f};

  const int srow = tid >> 2;
  const int scol = (tid & 3) * 8;
  const u16* gA0 = A + (size_t)(m0 + srow) * lda + scol;
  const u16* gA1 = A + (size_t)(m0 + 64 + srow) * lda + scol;
  const u16* gB0 = Bt + (size_t)(n0 + srow) * ldb + scol;
  const u16* gB1 = Bt + (size_t)(n0 + 64 + srow) * ldb + scol;  // BN==128 only

  for (int kb = 0; kb < K; kb += 64) {
#pragma unroll
    for (int h = 0; h < 2; ++h) {
      const int kh = kb + h * 32;
      async16(gA0 + kh, As + h * 4096 + tid * 8);
      async16(gA1 + kh, As + h * 4096 + 2048 + tid * 8);
      async16(gB0 + kh, Bs + h * BHALF + tid * 8);
      if constexpr (BN == 128) async16(gB1 + kh, Bs + h * BHALF + 2048 + tid * 8);
    }
    __syncthreads();
#pragma unroll
    for (int h = 0; h < 2; ++h) {
      f16x8 af[4], bfr[NJ];
#pragma unroll
      for (int i = 0; i < 4; ++i)
        af[i] = *(const f16x8*)(&As[h * 4096 + (wm * 64 + i * 16 + lr) * 32 + lq * 8]);
#pragma unroll
      for (int j = 0; j < NJ; ++j)
        bfr[j] = *(const f16x8*)(&Bs[h * BHALF + (wn * (BN / 2) + j * 16 + lr) * 32 + lq * 8]);
#pragma unroll
      for (int i = 0; i < 4; ++i)
#pragma unroll
        for (int j = 0; j < NJ; ++j)
          acc[i][j] = __builtin_amdgcn_mfma_f32_16x16x32_f16(af[i], bfr[j],
                                                             acc[i][j], 0, 0, 0);
    }
    __syncthreads();
  }

#pragma unroll
  for (int i = 0; i < 4; ++i)
#pragma unroll
    for (int j = 0; j < NJ; ++j) {
      const int col = n0 + wn * (BN / 2) + j * 16 + lr;
#pragma unroll
      for (int r = 0; r < 4; ++r) {
        const int row = m0 + wm * 64 + i * 16 + lq * 4 + r;
        const float v = acc[i][j][r];
        if constexpr (std::is_same_v<OT, float>) {
          C[(size_t)row * ldc + col] = v;
        } else {
          C[(size_t)row * ldc + col] = f2hu(v);
        }
      }
    }
}

// ---------------------------------------------------------------------------
// out[i] = sum of 2 split-K partials (f32), float4-vectorized.
// ---------------------------------------------------------------------------
__global__ void reduce2(const float* __restrict__ q2, float* __restrict__ out) {
  const size_t i = ((size_t)blockIdx.x * 256 + threadIdx.x) * 4;
  const size_t S = (size_t)2048 * 1024;
  float4 a = *(const float4*)(q2 + i);
  const float4 b = *(const float4*)(q2 + S + i);
  a.x += b.x;
  a.y += b.y;
  a.z += b.z;
  a.w += b.w;
  *(float4*)(out + i) = a;
}

// ---------------------------------------------------------------------------
// qsum = sum of 11 split-K partials of the metric-conv GEMM output.
// ---------------------------------------------------------------------------
__global__ __launch_bounds__(256)
void presum11(const float* __restrict__ q, float* __restrict__ qsum) {
  const size_t i = ((size_t)blockIdx.x * 256 + threadIdx.x) * 4;
  float4 s = *(const float4*)(q + i);
#pragma unroll
  for (int ks = 1; ks < 11; ++ks) {
    const float4 v = *(const float4*)(q + (size_t)ks * 131072 + i);
    s.x += v.x; s.y += v.y; s.z += v.z; s.w += v.w;
  }
  *(float4*)(qsum + i) = s;
}

// ---------------------------------------------------------------------------
// Fused gate/up GEMM + SiLU (bf16 MFMA, f16 output), 128x64 tile, BK=64
// two-half single-buffer staging (32 KB LDS). Grid (44, 16): B-tiles
// XCD-pinned. 3 blocks/CU.
// ---------------------------------------------------------------------------
__global__ __launch_bounds__(256, 3)
void gateup_gemm(const u16* __restrict__ x, const u16* __restrict__ wgu,
                 u16* __restrict__ xffn) {
  constexpr int K = 1024;
  __shared__ u16 As[2 * 128 * 32];
  __shared__ u16 Bgs[2 * 64 * 32];
  __shared__ u16 Bus[2 * 64 * 32];
  const int n0 = blockIdx.x * 64;   // 44 n-tiles (fast dim -> XCD pinning)
  const int m0 = blockIdx.y * 128;  // 16 m-tiles
  const int tid = threadIdx.x;
  const int lane = tid & 63;
  const int wv = tid >> 6;
  const int wm = wv & 1, wn = wv >> 1;
  const int lr = lane & 15;
  const int lq = lane >> 4;

  f32x4 accg[4][2], accu[4][2];
#pragma unroll
  for (int i = 0; i < 4; ++i)
#pragma unroll
    for (int j = 0; j < 2; ++j) {
      accg[i][j] = (f32x4){0.f, 0.f, 0.f, 0.f};
      accu[i][j] = (f32x4){0.f, 0.f, 0.f, 0.f};
    }

  const int srow = tid >> 2;
  const int scol = (tid & 3) * 8;
  const u16* gA0 = x + (size_t)(m0 + srow) * K + scol;
  const u16* gA1 = x + (size_t)(m0 + 64 + srow) * K + scol;
  const u16* gBg = wgu + (size_t)(n0 + srow) * K + scol;
  const u16* gBu = wgu + (size_t)(INTER + n0 + srow) * K + scol;

  for (int kb = 0; kb < K; kb += 64) {
#pragma unroll
    for (int h = 0; h < 2; ++h) {
      const int kh = kb + h * 32;
      async16(gA0 + kh, As + h * 4096 + tid * 8);
      async16(gA1 + kh, As + h * 4096 + 2048 + tid * 8);
      async16(gBg + kh, Bgs + h * 2048 + tid * 8);
      async16(gBu + kh, Bus + h * 2048 + tid * 8);
    }
    __syncthreads();
#pragma unroll
    for (int h = 0; h < 2; ++h) {
      bf16x8 af[4], bg[2], bu[2];
#pragma unroll
      for (int i = 0; i < 4; ++i)
        af[i] = *(const bf16x8*)(&As[h * 4096 + (wm * 64 + i * 16 + lr) * 32 + lq * 8]);
#pragma unroll
      for (int j = 0; j < 2; ++j) {
        bg[j] = *(const bf16x8*)(&Bgs[h * 2048 + (wn * 32 + j * 16 + lr) * 32 + lq * 8]);
        bu[j] = *(const bf16x8*)(&Bus[h * 2048 + (wn * 32 + j * 16 + lr) * 32 + lq * 8]);
      }
#pragma unroll
      for (int i = 0; i < 4; ++i)
#pragma unroll
        for (int j = 0; j < 2; ++j) {
          accg[i][j] = __builtin_amdgcn_mfma_f32_16x16x32_bf16(af[i], bg[j],
                                                               accg[i][j], 0, 0, 0);
          accu[i][j] = __builtin_amdgcn_mfma_f32_16x16x32_bf16(af[i], bu[j],
                                                               accu[i][j], 0, 0, 0);
        }
    }
    __syncthreads();
  }

#pragma unroll
  for (int i = 0; i < 4; ++i)
#pragma unroll
    for (int j = 0; j < 2; ++j) {
      const int col = n0 + wn * 32 + j * 16 + lr;
#pragma unroll
      for (int r = 0; r < 4; ++r) {
        const int row = m0 + wm * 64 + i * 16 + lq * 4 + r;
        const float g = accg[i][j][r];
        const float u = accu[i][j][r];
        const float s = g / (1.f + __expf(-g));
        xffn[(size_t)row * INTER + col] = f2hu(s * u);  // f16 out
      }
    }
}

// ---------------------------------------------------------------------------
// Fused: 9-tap shifted sum + offsets -> tap records, reading the presummed
// q plane. 256 threads cooperate on the window load; wave 0 computes the
// 64 pixels after the barrier. (f32 path, unchanged.)
// ---------------------------------------------------------------------------
__global__ __launch_bounds__(256)
void offsets_fused(const float* __restrict__ qsum,  // [2048][64]
                   const float* __restrict__ b_metric,
                   float4* __restrict__ wrec, int4* __restrict__ orec) {
  __shared__ float lds[130 * 65];
  const int chunk = blockIdx.x;      // 0..31
  const int b = chunk >> 4;
  const int c0 = (chunk & 15) * 64;
  const int t = threadIdx.x;         // 0..255

  for (int v = t; v < 130 * 16; v += 256) {
    const int row = v >> 4;
    const int c4 = (v & 15) * 4;
    int pg = c0 - 33 + row;
    pg = min(max(pg, 0), 1023);
    const float4 s = *(const float4*)(qsum + ((size_t)b * 1024 + pg) * 64 + c4);
    float* d = &lds[row * 65 + c4];
    d[0] = s.x; d[1] = s.y; d[2] = s.z; d[3] = s.w;
  }
  __syncthreads();
  if (t >= 64) return;

  const int pix = c0 + t;
  const int i = pix >> 5, j = pix & 31;
  float p[7];
#pragma unroll
  for (int o = 0; o < 7; ++o) p[o] = b_metric[o];
#pragma unroll
  for (int tap = 0; tap < 9; ++tap) {
    const int dy = tap / 3 - 1, dx = tap % 3 - 1;
    const int ii = i + dy, jj = j + dx;
    if ((unsigned)ii < 32u && (unsigned)jj < 32u) {
      const float* r = &lds[(t + 33 + dy * 32 + dx) * 65 + tap];
#pragma unroll
      for (int o = 0; o < 7; ++o) p[o] += r[o * 9];
    }
  }
  const float m00 = p[0], m01 = p[1], m10 = p[2], m11 = p[3];
  const float dry = p[4], drx = p[5];
  const float sc = tanhf(p[6]);
#pragma unroll
  for (int k = 0; k < 9; ++k) {
    const float pyk = (float)(k / 3 - 1), pxk = (float)(k % 3 - 1);
    const float offy = sc * (m00 * pyk + m01 * pxk) + dry;
    const float offx = sc * (m10 * pyk + m11 * pxk) + drx;
    const float posy = (float)i + pyk + offy;
    const float posx = (float)j + pxk + offx;
    const float y0f = floorf(posy), x0f = floorf(posx);
    const int y0 = (int)y0f, x0 = (int)x0f;
    const float ty = posy - y0f, tx = posx - x0f;
    const int y1 = y0 + 1, x1 = x0 + 1;
    const float vy0 = ((unsigned)y0 < 32u) ? 1.f : 0.f;
    const float vy1 = ((unsigned)y1 < 32u) ? 1.f : 0.f;
    const float vx0 = ((unsigned)x0 < 32u) ? 1.f : 0.f;
    const float vx1 = ((unsigned)x1 < 32u) ? 1.f : 0.f;
    float4 w;
    w.x = (1.f - ty) * (1.f - tx) * vy0 * vx0;
    w.y = (1.f - ty) * tx * vy0 * vx1;
    w.z = ty * (1.f - tx) * vy1 * vx0;
    w.w = ty * tx * vy1 * vx1;
    const int cy0 = min(max(y0, 0), 31), cy1 = min(max(y1, 0), 31);
    const int cx0 = min(max(x0, 0), 31), cx1 = min(max(x1, 0), 31);
    int4 o;
    o.x = (cy0 * 32 + cx0) * (INTER * 2);  // byte offsets within batch image
    o.y = (cy0 * 32 + cx1) * (INTER * 2);
    o.z = (cy1 * 32 + cx0) * (INTER * 2);
    o.w = (cy1 * 32 + cx1) * (INTER * 2);
    const size_t r = (((size_t)b * 9 + k) << 10) + pix;
    wrec[r] = w;
    orec[r] = o;
  }
}

// ---------------------------------------------------------------------------
// Deformable depthwise conv, 8 channels/thread, PACKED f16 math
// (v_pk_fma_f16 via __hfma2). Records LDS-staged; XCD-local swizzle.
// ---------------------------------------------------------------------------
__global__ __launch_bounds__(256)
void deform_kernel(const u16* __restrict__ xffn,      // f16
                   const float4* __restrict__ wrec,
                   const int4* __restrict__ orec,
                   const u16* __restrict__ cwb,       // f16
                   const float* __restrict__ conv_b,
                   u16* __restrict__ gridout) {       // f16
  __shared__ float4 sw[2][9];
  __shared__ int4 so[2][9];
  const unsigned bid = (blockIdx.x & 7u) * 352u + (blockIdx.x >> 3);
  const unsigned t0 = bid * 256;
  const unsigned p0 = t0 / 352u;          // first pixel touched by block
  const unsigned t = t0 + threadIdx.x;
  const unsigned pix = t / 352u;
  const unsigned cv = t - pix * 352u;
  const int c0 = cv * 8;
  const int b = pix >> 10, l = pix & 1023;

  if (threadIdx.x < 36) {                 // 2 pixels x 9 taps x {wrec,orec}
    const int pp = threadIdx.x / 18;
    const int rr = threadIdx.x - pp * 18;
    const int k = (rr < 9) ? rr : rr - 9;
    const unsigned pixel = p0 + pp;
    if (pixel < 2048) {
      const int bb = pixel >> 10, ll = pixel & 1023;
      const size_t r = (((size_t)bb * 9 + k) << 10) + ll;
      if (rr < 9) sw[pp][k] = wrec[r];
      else        so[pp][k] = orec[r];
    }
  }
  __syncthreads();

  const int pp = (int)(pix - p0);         // 0 or 1

  union U8 { u16x8 u; __half2 h[4]; uint4 q; };

  __half2 acc2[4];
  {
    const float4 b0 = *(const float4*)(&conv_b[c0]);
    const float4 b1 = *(const float4*)(&conv_b[c0 + 4]);
    acc2[0] = __floats2half2_rn(b0.x, b0.y);
    acc2[1] = __floats2half2_rn(b0.z, b0.w);
    acc2[2] = __floats2half2_rn(b1.x, b1.y);
    acc2[3] = __floats2half2_rn(b1.z, b1.w);
  }
  const char* xb = (const char*)xffn +
                   ((size_t)b * 1024 * INTER + c0) * sizeof(u16);
#pragma unroll
  for (int k = 0; k < 9; ++k) {
    const float4 w = sw[pp][k];
    const int4 o = so[pp][k];
    const __half2 wx = __float2half2_rn(w.x);
    const __half2 wy = __float2half2_rn(w.y);
    const __half2 wz = __float2half2_rn(w.z);
    const __half2 ww = __float2half2_rn(w.w);
    U8 v00, v01, v10, v11, cw;
    v00.u = *(const u16x8*)(xb + o.x);
    v01.u = *(const u16x8*)(xb + o.y);
    v10.u = *(const u16x8*)(xb + o.z);
    v11.u = *(const u16x8*)(xb + o.w);
    cw.u = *(const u16x8*)(&cwb[(size_t)k * INTER + c0]);
#pragma unroll
    for (int p = 0; p < 4; ++p) {
      __half2 bl = __hmul2(wx, v00.h[p]);
      bl = __hfma2(wy, v01.h[p], bl);
      bl = __hfma2(wz, v10.h[p], bl);
      bl = __hfma2(ww, v11.h[p], bl);
      acc2[p] = __hfma2(bl, cw.h[p], acc2[p]);
    }
  }
  U8 outv;
#pragma unroll
  for (int p = 0; p < 4; ++p) outv.h[p] = acc2[p];
  *(uint4*)(gridout + ((size_t)b * 1024 + l) * INTER + c0) = outv.q;
}

// ---------------------------------------------------------------------------
extern "C" void kernel_launch(void* const* d_in, const int* in_sizes, int n_in,
                              void* d_out, int out_size, void* d_ws,
                              size_t ws_size, hipStream_t stream) {
  const float* x         = (const float*)d_in[0];
  const float* w_gate_up = (const float*)d_in[1];
  const float* w_metric  = (const float*)d_in[2];
  const float* b_metric  = (const float*)d_in[3];
  const float* conv_w    = (const float*)d_in[4];
  const float* conv_b    = (const float*)d_in[5];
  const float* w_down    = (const float*)d_in[6];
  float* out = (float*)d_out;

  // Workspace (~50 MB peak). Lifetimes:
  //   gridout [0, 11.53)  f16    step 5 -> 6
  //   q2      [12, 28.8)  f32    step 6 -> 7 (2 split-K partials); region
  //   shared (earlier steps):
  //     xffn   [12, 23.6)  f16   step 2 -> 5
  //     xbf    [24, 28.2)  bf16  step 1 -> 2
  //     wgubf  [28.25, 39.8) bf16 step 1 -> 2
  //     q_conv [28.25, 34.1) f32 step 3 -> 4a (11 partials, overlays wgubf)
  //     qsum   [36, 36.5)  f32   step 4a -> 4b
  //     wm2    [40, 40.36) f16   step 1 -> 3 (64 rows)
  //     cwb    [41, 41.05) f16   step 1 -> 5
  //     wrec   [42, 42.3)  f32x4 step 4 -> 5
  //     orec   [43, 43.3)  int4  step 4 -> 5
  //   wdbf    [44, 49.8)  f16    step 1 -> 6
  char* w = (char*)d_ws;
  u16* gridout  = (u16*)(w);
  float* q2     = (float*)(w + (12u << 20));
  u16* xffn     = (u16*)(w + (12u << 20));
  u16* xbf      = (u16*)(w + (24u << 20));
  u16* wgubf    = (u16*)(w + (28u << 20) + (256u << 10));
  float* q_conv = (float*)(w + (28u << 20) + (256u << 10));
  float* qsum   = (float*)(w + (36u << 20));
  u16* wm2      = (u16*)(w + (40u << 20));
  u16* cwb      = (u16*)(w + (41u << 20));
  float4* wrec  = (float4*)(w + (42u << 20));
  int4* orec    = (int4*)(w + (43u << 20));
  u16* wdbf     = (u16*)(w + (44u << 20));

  // 1) fused bf16/f16 conversions + weight repacks
  prep_all<<<6051, 256, 0, stream>>>(x, w_gate_up, w_down, w_metric, conv_w,
                                     xbf, wgubf, wdbf, wm2, cwb);
  // 2) x_ffn = silu(x@Wg^T) * (x@Wu^T)  (bf16 MFMA, f16 out; grid (44,16))
  gateup_gemm<<<dim3(44, 16), 256, 0, stream>>>(xbf, wgubf, xffn);
  // 3) metric conv as GEMM (f16), BN=64, split-K x11 (K=256)
  gemm_nt<64, false, float><<<dim3(16, 1, 11), 256, 0, stream>>>(
      xffn, INTER, wm2, INTER, q_conv, 2048, 64, 256);
  // 4a) full-parallelism partial-sum (11 planes -> 1)
  presum11<<<128, 256, 0, stream>>>(q_conv, qsum);
  // 4b) fused tap-sum + offsets -> tap records (256-thread window load)
  offsets_fused<<<32, 256, 0, stream>>>(qsum, b_metric, wrec, orec);
  // 5) deformable depthwise conv (packed f16 math, LDS-staged records)
  deform_kernel<<<2816, 256, 0, stream>>>(xffn, wrec, orec, cwb, conv_b,
                                          gridout);
  // 6) GEMM2 (f16) split-K x2, BN=64, grid (16,16,2) n-fast (XCD-pinned B):
  //    halves the 33.5 MB partial round-trip vs split-K x4 at equal
  //    parallelism (512 blocks = 2/CU). K slice = 1408 = 22*64.
  gemm_nt<64, true, float><<<dim3(16, 16, 2), 256, 0, stream>>>(
      gridout, INTER, wdbf, INTER, q2, 2048, 1024, 1408);
  // 7) out = sum of 2 partials (deterministic, no cross-XCD atomics)
  reduce2<<<2048, 256, 0, stream>>>(q2, out);
}

// Round 9
// 188.664 us; speedup vs baseline: 1.0165x; 1.0040x over previous
//
#include <hip/hip_runtime.h>
#include <hip/hip_bf16.h>
#include <hip/hip_fp16.h>
#include <cstdint>
#include <cstddef>
#include <type_traits>

#define INTER 2816

typedef __bf16 bf16x8 __attribute__((ext_vector_type(8)));
typedef _Float16 f16x8 __attribute__((ext_vector_type(8)));
typedef float f32x4 __attribute__((ext_vector_type(4)));
typedef unsigned short u16x8 __attribute__((ext_vector_type(8)));
using bf16 = __hip_bfloat16;
using u16 = unsigned short;

__device__ __forceinline__ u16 f2bu(float f) {
  bf16 h = __float2bfloat16(f);
  return *reinterpret_cast<u16*>(&h);
}
__device__ __forceinline__ u16 f2hu(float f) {
  __half h = __float2half(f);
  return *reinterpret_cast<u16*>(&h);
}

// Async global->LDS DMA, 16 B per lane (wave-uniform base + lane*16).
__device__ __forceinline__ void async16(const u16* g, u16* l) {
  __builtin_amdgcn_global_load_lds(
      (const __attribute__((address_space(1))) unsigned int*)g,
      (__attribute__((address_space(3))) unsigned int*)l, 16, 0, 0);
}

// Stage 8 contiguous f32 as bf16 (H=false) or f16 (H=true), 16B out.
template <bool H>
__device__ __forceinline__ void stage8(u16* dst, const float* src) {
  const float4 a = *(const float4*)(src);
  const float4 b = *(const float4*)(src + 4);
  u16 tmp[8];
  if constexpr (H) {
    tmp[0] = f2hu(a.x); tmp[1] = f2hu(a.y); tmp[2] = f2hu(a.z); tmp[3] = f2hu(a.w);
    tmp[4] = f2hu(b.x); tmp[5] = f2hu(b.y); tmp[6] = f2hu(b.z); tmp[7] = f2hu(b.w);
  } else {
    tmp[0] = f2bu(a.x); tmp[1] = f2bu(a.y); tmp[2] = f2bu(a.z); tmp[3] = f2bu(a.w);
    tmp[4] = f2bu(b.x); tmp[5] = f2bu(b.y); tmp[6] = f2bu(b.z); tmp[7] = f2bu(b.w);
  }
  *(uint4*)dst = *(uint4*)tmp;
}

// ---------------------------------------------------------------------------
// Fused one-shot prep. x/wgu stay bf16 (feed the bf16 gateup MFMA); wd, wm2,
// cwb become f16 (feed the f16 pipeline: conv GEMM, deform, gemm2).
// wm2: 64 x INTER f16 (63 metric rows + 1 zero pad). cwb: 9 x INTER f16.
// ---------------------------------------------------------------------------
__global__ __launch_bounds__(256)
void prep_all(const float* __restrict__ x, const float* __restrict__ wgu,
              const float* __restrict__ wd, const float* __restrict__ w_metric,
              const float* __restrict__ conv_w, u16* __restrict__ xbf,
              u16* __restrict__ wgubf, u16* __restrict__ wdbf,
              u16* __restrict__ wm2, u16* __restrict__ cwb) {
  constexpr size_t S0 = (size_t)2048 * 1024;
  constexpr size_t S1 = (size_t)5632 * 1024;
  constexpr size_t S2 = (size_t)1024 * 2816;
  constexpr size_t NCONV_THREADS = (S0 + S1 + S2) / 8;  // 1343488 = 5248 blks
  const size_t t = (size_t)blockIdx.x * 256 + threadIdx.x;
  if (t < NCONV_THREADS) {
    const size_t e0 = t * 8;
    if (e0 < S0) {
      stage8<false>(xbf + e0, x + e0);
    } else if (e0 < S0 + S1) {
      stage8<false>(wgubf + (e0 - S0), wgu + (e0 - S0));
    } else {
      stage8<true>(wdbf + (e0 - S0 - S1), wd + (e0 - S0 - S1));
    }
  } else {
    const unsigned p = (unsigned)(t - NCONV_THREADS);  // 0..205567 (73 rows)
    const unsigned y = p / 2816u;                      // 0..72
    const unsigned c = p - y * 2816u;
    if (y < 64) {
      float v = 0.f;
      if (y < 63) {
        const unsigned o = y / 9, tap = y - o * 9;
        v = w_metric[((size_t)o * INTER + c) * 9 + tap];
      }
      wm2[(size_t)y * INTER + c] = f2hu(v);
    } else {
      const unsigned k = y - 64;
      cwb[(size_t)k * INTER + c] = f2hu(conv_w[(size_t)c * 9 + k]);
    }
  }
}

// ---------------------------------------------------------------------------
// NT GEMM (f16 inputs), BMxBN tile (BM in {64,128}), BK=64 staged as two
// BK=32 half-tiles (single buffer, one barrier-pair per 64 K-elements).
// 4 waves (2m x 2n), 16x16x32 f16 mfma. BM=64 variant exists to raise
// grid-level parallelism on small-N GEMMs (conv: 176 -> 352 blocks).
// NSWAP puts the n-tile on blockIdx.x for XCD pinning of B. Split-K via
// grid.z writes partial C at z*M*ldc. K must be a multiple of 64.
// ---------------------------------------------------------------------------
template <int BM, int BN, bool NSWAP, typename OT>
__global__ __launch_bounds__(256, 3)
void gemm_nt(const u16* __restrict__ A, int lda, const u16* __restrict__ Bt,
             int ldb, OT* __restrict__ C, int M, int ldc, int K) {
  constexpr int MI = BM / 32;      // m-frags per wave (wave spans BM/2 rows)
  constexpr int NJ = BN / 32;      // n-frags per wave
  constexpr int AHALF = BM * 32;   // u16 per A half-tile
  constexpr int BHALF = BN * 32;   // u16 per B half-tile
  __shared__ u16 As[2 * AHALF];
  __shared__ u16 Bs[2 * BHALF];
  const size_t koff = (size_t)blockIdx.z * K;
  A += koff;
  Bt += koff;
  C += (size_t)blockIdx.z * M * ldc;
  const int m0 = (NSWAP ? blockIdx.y : blockIdx.x) * BM;
  const int n0 = (NSWAP ? blockIdx.x : blockIdx.y) * BN;
  const int tid = threadIdx.x;
  const int lane = tid & 63;
  const int wv = tid >> 6;
  const int wm = wv & 1, wn = wv >> 1;
  const int lr = lane & 15;
  const int lq = lane >> 4;

  f32x4 acc[MI][NJ];
#pragma unroll
  for (int i = 0; i < MI; ++i)
#pragma unroll
    for (int j = 0; j < NJ; ++j) acc[i][j] = (f32x4){0.f, 0.f, 0.f, 0.f};

  const int srow = tid >> 2;
  const int scol = (tid & 3) * 8;
  const u16* gA0 = A + (size_t)(m0 + srow) * lda + scol;
  const u16* gA1 = A + (size_t)(m0 + 64 + srow) * lda + scol;  // BM==128 only
  const u16* gB0 = Bt + (size_t)(n0 + srow) * ldb + scol;
  const u16* gB1 = Bt + (size_t)(n0 + 64 + srow) * ldb + scol; // BN==128 only

  for (int kb = 0; kb < K; kb += 64) {
#pragma unroll
    for (int h = 0; h < 2; ++h) {
      const int kh = kb + h * 32;
      async16(gA0 + kh, As + h * AHALF + tid * 8);
      if constexpr (BM == 128)
        async16(gA1 + kh, As + h * AHALF + 2048 + tid * 8);
      async16(gB0 + kh, Bs + h * BHALF + tid * 8);
      if constexpr (BN == 128)
        async16(gB1 + kh, Bs + h * BHALF + 2048 + tid * 8);
    }
    __syncthreads();
#pragma unroll
    for (int h = 0; h < 2; ++h) {
      f16x8 af[MI], bfr[NJ];
#pragma unroll
      for (int i = 0; i < MI; ++i)
        af[i] = *(const f16x8*)(&As[h * AHALF + (wm * (BM / 2) + i * 16 + lr) * 32 + lq * 8]);
#pragma unroll
      for (int j = 0; j < NJ; ++j)
        bfr[j] = *(const f16x8*)(&Bs[h * BHALF + (wn * (BN / 2) + j * 16 + lr) * 32 + lq * 8]);
#pragma unroll
      for (int i = 0; i < MI; ++i)
#pragma unroll
        for (int j = 0; j < NJ; ++j)
          acc[i][j] = __builtin_amdgcn_mfma_f32_16x16x32_f16(af[i], bfr[j],
                                                             acc[i][j], 0, 0, 0);
    }
    __syncthreads();
  }

#pragma unroll
  for (int i = 0; i < MI; ++i)
#pragma unroll
    for (int j = 0; j < NJ; ++j) {
      const int col = n0 + wn * (BN / 2) + j * 16 + lr;
#pragma unroll
      for (int r = 0; r < 4; ++r) {
        const int row = m0 + wm * (BM / 2) + i * 16 + lq * 4 + r;
        const float v = acc[i][j][r];
        if constexpr (std::is_same_v<OT, float>) {
          C[(size_t)row * ldc + col] = v;
        } else {
          C[(size_t)row * ldc + col] = f2hu(v);
        }
      }
    }
}

// ---------------------------------------------------------------------------
// out[i] = sum of 2 split-K partials (f32), float4-vectorized.
// ---------------------------------------------------------------------------
__global__ void reduce2(const float* __restrict__ q2, float* __restrict__ out) {
  const size_t i = ((size_t)blockIdx.x * 256 + threadIdx.x) * 4;
  const size_t S = (size_t)2048 * 1024;
  float4 a = *(const float4*)(q2 + i);
  const float4 b = *(const float4*)(q2 + S + i);
  a.x += b.x;
  a.y += b.y;
  a.z += b.z;
  a.w += b.w;
  *(float4*)(out + i) = a;
}

// ---------------------------------------------------------------------------
// qsum = sum of 11 split-K partials of the metric-conv GEMM output.
// ---------------------------------------------------------------------------
__global__ __launch_bounds__(256)
void presum11(const float* __restrict__ q, float* __restrict__ qsum) {
  const size_t i = ((size_t)blockIdx.x * 256 + threadIdx.x) * 4;
  float4 s = *(const float4*)(q + i);
#pragma unroll
  for (int ks = 1; ks < 11; ++ks) {
    const float4 v = *(const float4*)(q + (size_t)ks * 131072 + i);
    s.x += v.x; s.y += v.y; s.z += v.z; s.w += v.w;
  }
  *(float4*)(qsum + i) = s;
}

// ---------------------------------------------------------------------------
// Fused gate/up GEMM + SiLU (bf16 MFMA, f16 output), 128x64 tile, BK=64
// two-half single-buffer staging (32 KB LDS). Grid (44, 16): B-tiles
// XCD-pinned. 3 blocks/CU.
// ---------------------------------------------------------------------------
__global__ __launch_bounds__(256, 3)
void gateup_gemm(const u16* __restrict__ x, const u16* __restrict__ wgu,
                 u16* __restrict__ xffn) {
  constexpr int K = 1024;
  __shared__ u16 As[2 * 128 * 32];
  __shared__ u16 Bgs[2 * 64 * 32];
  __shared__ u16 Bus[2 * 64 * 32];
  const int n0 = blockIdx.x * 64;   // 44 n-tiles (fast dim -> XCD pinning)
  const int m0 = blockIdx.y * 128;  // 16 m-tiles
  const int tid = threadIdx.x;
  const int lane = tid & 63;
  const int wv = tid >> 6;
  const int wm = wv & 1, wn = wv >> 1;
  const int lr = lane & 15;
  const int lq = lane >> 4;

  f32x4 accg[4][2], accu[4][2];
#pragma unroll
  for (int i = 0; i < 4; ++i)
#pragma unroll
    for (int j = 0; j < 2; ++j) {
      accg[i][j] = (f32x4){0.f, 0.f, 0.f, 0.f};
      accu[i][j] = (f32x4){0.f, 0.f, 0.f, 0.f};
    }

  const int srow = tid >> 2;
  const int scol = (tid & 3) * 8;
  const u16* gA0 = x + (size_t)(m0 + srow) * K + scol;
  const u16* gA1 = x + (size_t)(m0 + 64 + srow) * K + scol;
  const u16* gBg = wgu + (size_t)(n0 + srow) * K + scol;
  const u16* gBu = wgu + (size_t)(INTER + n0 + srow) * K + scol;

  for (int kb = 0; kb < K; kb += 64) {
#pragma unroll
    for (int h = 0; h < 2; ++h) {
      const int kh = kb + h * 32;
      async16(gA0 + kh, As + h * 4096 + tid * 8);
      async16(gA1 + kh, As + h * 4096 + 2048 + tid * 8);
      async16(gBg + kh, Bgs + h * 2048 + tid * 8);
      async16(gBu + kh, Bus + h * 2048 + tid * 8);
    }
    __syncthreads();
#pragma unroll
    for (int h = 0; h < 2; ++h) {
      bf16x8 af[4], bg[2], bu[2];
#pragma unroll
      for (int i = 0; i < 4; ++i)
        af[i] = *(const bf16x8*)(&As[h * 4096 + (wm * 64 + i * 16 + lr) * 32 + lq * 8]);
#pragma unroll
      for (int j = 0; j < 2; ++j) {
        bg[j] = *(const bf16x8*)(&Bgs[h * 2048 + (wn * 32 + j * 16 + lr) * 32 + lq * 8]);
        bu[j] = *(const bf16x8*)(&Bus[h * 2048 + (wn * 32 + j * 16 + lr) * 32 + lq * 8]);
      }
#pragma unroll
      for (int i = 0; i < 4; ++i)
#pragma unroll
        for (int j = 0; j < 2; ++j) {
          accg[i][j] = __builtin_amdgcn_mfma_f32_16x16x32_bf16(af[i], bg[j],
                                                               accg[i][j], 0, 0, 0);
          accu[i][j] = __builtin_amdgcn_mfma_f32_16x16x32_bf16(af[i], bu[j],
                                                               accu[i][j], 0, 0, 0);
        }
    }
    __syncthreads();
  }

#pragma unroll
  for (int i = 0; i < 4; ++i)
#pragma unroll
    for (int j = 0; j < 2; ++j) {
      const int col = n0 + wn * 32 + j * 16 + lr;
#pragma unroll
      for (int r = 0; r < 4; ++r) {
        const int row = m0 + wm * 64 + i * 16 + lq * 4 + r;
        const float g = accg[i][j][r];
        const float u = accu[i][j][r];
        const float s = g / (1.f + __expf(-g));
        xffn[(size_t)row * INTER + col] = f2hu(s * u);  // f16 out
      }
    }
}

// ---------------------------------------------------------------------------
// Fused: 9-tap shifted sum + offsets -> tap records, reading the presummed
// q plane. 256 threads cooperate on the window load; wave 0 computes the
// 64 pixels after the barrier. (f32 path, unchanged.)
// ---------------------------------------------------------------------------
__global__ __launch_bounds__(256)
void offsets_fused(const float* __restrict__ qsum,  // [2048][64]
                   const float* __restrict__ b_metric,
                   float4* __restrict__ wrec, int4* __restrict__ orec) {
  __shared__ float lds[130 * 65];
  const int chunk = blockIdx.x;      // 0..31
  const int b = chunk >> 4;
  const int c0 = (chunk & 15) * 64;
  const int t = threadIdx.x;         // 0..255

  for (int v = t; v < 130 * 16; v += 256) {
    const int row = v >> 4;
    const int c4 = (v & 15) * 4;
    int pg = c0 - 33 + row;
    pg = min(max(pg, 0), 1023);
    const float4 s = *(const float4*)(qsum + ((size_t)b * 1024 + pg) * 64 + c4);
    float* d = &lds[row * 65 + c4];
    d[0] = s.x; d[1] = s.y; d[2] = s.z; d[3] = s.w;
  }
  __syncthreads();
  if (t >= 64) return;

  const int pix = c0 + t;
  const int i = pix >> 5, j = pix & 31;
  float p[7];
#pragma unroll
  for (int o = 0; o < 7; ++o) p[o] = b_metric[o];
#pragma unroll
  for (int tap = 0; tap < 9; ++tap) {
    const int dy = tap / 3 - 1, dx = tap % 3 - 1;
    const int ii = i + dy, jj = j + dx;
    if ((unsigned)ii < 32u && (unsigned)jj < 32u) {
      const float* r = &lds[(t + 33 + dy * 32 + dx) * 65 + tap];
#pragma unroll
      for (int o = 0; o < 7; ++o) p[o] += r[o * 9];
    }
  }
  const float m00 = p[0], m01 = p[1], m10 = p[2], m11 = p[3];
  const float dry = p[4], drx = p[5];
  const float sc = tanhf(p[6]);
#pragma unroll
  for (int k = 0; k < 9; ++k) {
    const float pyk = (float)(k / 3 - 1), pxk = (float)(k % 3 - 1);
    const float offy = sc * (m00 * pyk + m01 * pxk) + dry;
    const float offx = sc * (m10 * pyk + m11 * pxk) + drx;
    const float posy = (float)i + pyk + offy;
    const float posx = (float)j + pxk + offx;
    const float y0f = floorf(posy), x0f = floorf(posx);
    const int y0 = (int)y0f, x0 = (int)x0f;
    const float ty = posy - y0f, tx = posx - x0f;
    const int y1 = y0 + 1, x1 = x0 + 1;
    const float vy0 = ((unsigned)y0 < 32u) ? 1.f : 0.f;
    const float vy1 = ((unsigned)y1 < 32u) ? 1.f : 0.f;
    const float vx0 = ((unsigned)x0 < 32u) ? 1.f : 0.f;
    const float vx1 = ((unsigned)x1 < 32u) ? 1.f : 0.f;
    float4 w;
    w.x = (1.f - ty) * (1.f - tx) * vy0 * vx0;
    w.y = (1.f - ty) * tx * vy0 * vx1;
    w.z = ty * (1.f - tx) * vy1 * vx0;
    w.w = ty * tx * vy1 * vx1;
    const int cy0 = min(max(y0, 0), 31), cy1 = min(max(y1, 0), 31);
    const int cx0 = min(max(x0, 0), 31), cx1 = min(max(x1, 0), 31);
    int4 o;
    o.x = (cy0 * 32 + cx0) * (INTER * 2);  // byte offsets within batch image
    o.y = (cy0 * 32 + cx1) * (INTER * 2);
    o.z = (cy1 * 32 + cx0) * (INTER * 2);
    o.w = (cy1 * 32 + cx1) * (INTER * 2);
    const size_t r = (((size_t)b * 9 + k) << 10) + pix;
    wrec[r] = w;
    orec[r] = o;
  }
}

// ---------------------------------------------------------------------------
// Deformable depthwise conv, 8 channels/thread, PACKED f16 math
// (v_pk_fma_f16 via __hfma2). Records LDS-staged; XCD-local swizzle.
// ---------------------------------------------------------------------------
__global__ __launch_bounds__(256)
void deform_kernel(const u16* __restrict__ xffn,      // f16
                   const float4* __restrict__ wrec,
                   const int4* __restrict__ orec,
                   const u16* __restrict__ cwb,       // f16
                   const float* __restrict__ conv_b,
                   u16* __restrict__ gridout) {       // f16
  __shared__ float4 sw[2][9];
  __shared__ int4 so[2][9];
  const unsigned bid = (blockIdx.x & 7u) * 352u + (blockIdx.x >> 3);
  const unsigned t0 = bid * 256;
  const unsigned p0 = t0 / 352u;          // first pixel touched by block
  const unsigned t = t0 + threadIdx.x;
  const unsigned pix = t / 352u;
  const unsigned cv = t - pix * 352u;
  const int c0 = cv * 8;
  const int b = pix >> 10, l = pix & 1023;

  if (threadIdx.x < 36) {                 // 2 pixels x 9 taps x {wrec,orec}
    const int pp = threadIdx.x / 18;
    const int rr = threadIdx.x - pp * 18;
    const int k = (rr < 9) ? rr : rr - 9;
    const unsigned pixel = p0 + pp;
    if (pixel < 2048) {
      const int bb = pixel >> 10, ll = pixel & 1023;
      const size_t r = (((size_t)bb * 9 + k) << 10) + ll;
      if (rr < 9) sw[pp][k] = wrec[r];
      else        so[pp][k] = orec[r];
    }
  }
  __syncthreads();

  const int pp = (int)(pix - p0);         // 0 or 1

  union U8 { u16x8 u; __half2 h[4]; uint4 q; };

  __half2 acc2[4];
  {
    const float4 b0 = *(const float4*)(&conv_b[c0]);
    const float4 b1 = *(const float4*)(&conv_b[c0 + 4]);
    acc2[0] = __floats2half2_rn(b0.x, b0.y);
    acc2[1] = __floats2half2_rn(b0.z, b0.w);
    acc2[2] = __floats2half2_rn(b1.x, b1.y);
    acc2[3] = __floats2half2_rn(b1.z, b1.w);
  }
  const char* xb = (const char*)xffn +
                   ((size_t)b * 1024 * INTER + c0) * sizeof(u16);
#pragma unroll
  for (int k = 0; k < 9; ++k) {
    const float4 w = sw[pp][k];
    const int4 o = so[pp][k];
    const __half2 wx = __float2half2_rn(w.x);
    const __half2 wy = __float2half2_rn(w.y);
    const __half2 wz = __float2half2_rn(w.z);
    const __half2 ww = __float2half2_rn(w.w);
    U8 v00, v01, v10, v11, cw;
    v00.u = *(const u16x8*)(xb + o.x);
    v01.u = *(const u16x8*)(xb + o.y);
    v10.u = *(const u16x8*)(xb + o.z);
    v11.u = *(const u16x8*)(xb + o.w);
    cw.u = *(const u16x8*)(&cwb[(size_t)k * INTER + c0]);
#pragma unroll
    for (int p = 0; p < 4; ++p) {
      __half2 bl = __hmul2(wx, v00.h[p]);
      bl = __hfma2(wy, v01.h[p], bl);
      bl = __hfma2(wz, v10.h[p], bl);
      bl = __hfma2(ww, v11.h[p], bl);
      acc2[p] = __hfma2(bl, cw.h[p], acc2[p]);
    }
  }
  U8 outv;
#pragma unroll
  for (int p = 0; p < 4; ++p) outv.h[p] = acc2[p];
  *(uint4*)(gridout + ((size_t)b * 1024 + l) * INTER + c0) = outv.q;
}

// ---------------------------------------------------------------------------
extern "C" void kernel_launch(void* const* d_in, const int* in_sizes, int n_in,
                              void* d_out, int out_size, void* d_ws,
                              size_t ws_size, hipStream_t stream) {
  const float* x         = (const float*)d_in[0];
  const float* w_gate_up = (const float*)d_in[1];
  const float* w_metric  = (const float*)d_in[2];
  const float* b_metric  = (const float*)d_in[3];
  const float* conv_w    = (const float*)d_in[4];
  const float* conv_b    = (const float*)d_in[5];
  const float* w_down    = (const float*)d_in[6];
  float* out = (float*)d_out;

  // Workspace (~50 MB peak). Lifetimes:
  //   gridout [0, 11.53)  f16    step 5 -> 6
  //   q2      [12, 28.8)  f32    step 6 -> 7 (2 split-K partials); region
  //   shared (earlier steps):
  //     xffn   [12, 23.6)  f16   step 2 -> 5
  //     xbf    [24, 28.2)  bf16  step 1 -> 2
  //     wgubf  [28.25, 39.8) bf16 step 1 -> 2
  //     q_conv [28.25, 34.1) f32 step 3 -> 4a (11 partials, overlays wgubf)
  //     qsum   [36, 36.5)  f32   step 4a -> 4b
  //     wm2    [40, 40.36) f16   step 1 -> 3 (64 rows)
  //     cwb    [41, 41.05) f16   step 1 -> 5
  //     wrec   [42, 42.3)  f32x4 step 4 -> 5
  //     orec   [43, 43.3)  int4  step 4 -> 5
  //   wdbf    [44, 49.8)  f16    step 1 -> 6
  char* w = (char*)d_ws;
  u16* gridout  = (u16*)(w);
  float* q2     = (float*)(w + (12u << 20));
  u16* xffn     = (u16*)(w + (12u << 20));
  u16* xbf      = (u16*)(w + (24u << 20));
  u16* wgubf    = (u16*)(w + (28u << 20) + (256u << 10));
  float* q_conv = (float*)(w + (28u << 20) + (256u << 10));
  float* qsum   = (float*)(w + (36u << 20));
  u16* wm2      = (u16*)(w + (40u << 20));
  u16* cwb      = (u16*)(w + (41u << 20));
  float4* wrec  = (float4*)(w + (42u << 20));
  int4* orec    = (int4*)(w + (43u << 20));
  u16* wdbf     = (u16*)(w + (44u << 20));

  // 1) fused bf16/f16 conversions + weight repacks
  prep_all<<<6051, 256, 0, stream>>>(x, w_gate_up, w_down, w_metric, conv_w,
                                     xbf, wgubf, wdbf, wm2, cwb);
  // 2) x_ffn = silu(x@Wg^T) * (x@Wu^T)  (bf16 MFMA, f16 out; grid (44,16))
  gateup_gemm<<<dim3(44, 16), 256, 0, stream>>>(xbf, wgubf, xffn);
  // 3) metric conv as GEMM (f16), BM=64 x BN=64, split-K x11: grid
  //    (32,1,11) = 352 blocks = 1.4/CU (was 176 = 0.69/CU idling 31% of
  //    the chip). K slice = 256 = 4 BK-64 iters.
  gemm_nt<64, 64, false, float><<<dim3(32, 1, 11), 256, 0, stream>>>(
      xffn, INTER, wm2, INTER, q_conv, 2048, 64, 256);
  // 4a) full-parallelism partial-sum (11 planes -> 1)
  presum11<<<128, 256, 0, stream>>>(q_conv, qsum);
  // 4b) fused tap-sum + offsets -> tap records (256-thread window load)
  offsets_fused<<<32, 256, 0, stream>>>(qsum, b_metric, wrec, orec);
  // 5) deformable depthwise conv (packed f16 math, LDS-staged records)
  deform_kernel<<<2816, 256, 0, stream>>>(xffn, wrec, orec, cwb, conv_b,
                                          gridout);
  // 6) GEMM2 (f16) split-K x2, BM=128 x BN=64, grid (16,16,2) n-fast
  //    (XCD-pinned B). K slice = 1408 = 22*64.
  gemm_nt<128, 64, true, float><<<dim3(16, 16, 2), 256, 0, stream>>>(
      gridout, INTER, wdbf, INTER, q2, 2048, 1024, 1408);
  // 7) out = sum of 2 partials (deterministic, no cross-XCD atomics)
  reduce2<<<2048, 256, 0, stream>>>(q2, out);
}